// Round 5
// baseline (200.629 us; speedup 1.0000x reference)
//
#include <hip/hip_runtime.h>

#define HH 512
#define WW 512
#define CH 3
#define NTX 64          // lanes per block row
#define NTY 4
#define PXT 2           // pixels per thread, horizontal
#define PYT 4           // pixels per thread, vertical
#define SPANX (NTX * PXT)        // 128 cols per block
#define SPANY (NTY * PYT)        // 16 rows per block
#define TILE_W (SPANX + 6)       // 134 logical cols
#define TILE_H (SPANY + 6)       // 22 rows
#define PHYS_W 138               // phys(133)=137 -> 138 slots per row

// exp(-50*d^2) * exp(-r2/4.5) == exp2(K1*d^2 + K2*r2)
#define K1f (-72.13475204444817f)   // -50 * log2(e)
#define K2f (-0.3205988979753252f)  // -(1/4.5) * log2(e)

__device__ __forceinline__ int reflect_idx(int v, int n) {
    v = (v < 0) ? -v : v;
    return (v >= n) ? (2 * (n - 1) - v) : v;
}

__device__ __forceinline__ float fast_exp2(float x) {
#if __has_builtin(__builtin_amdgcn_exp2f)
    return __builtin_amdgcn_exp2f(x);
#else
    return exp2f(x);
#endif
}

// skew: +1 slot every 32 logical cols -> stride-2 lane reads hit each bank exactly 2x (free)
__device__ __forceinline__ int phys(int c) { return c + (c >> 5); }

__global__ __launch_bounds__(NTX * NTY)
void bilateral_kernel(const float* __restrict__ in, float* __restrict__ out) {
    __shared__ float sm[CH * TILE_H * PHYS_W];   // 3*22*138*4 = 36432 B

    const int bx0 = blockIdx.x * SPANX;
    const int by0 = blockIdx.y * SPANY;
    const int b   = blockIdx.z;
    const float* inb = in + (size_t)b * CH * HH * WW;

    // ---- cooperative halo staging (lane-stride-1 b32 writes: conflict-free) ----
    for (int c = 0; c < CH; ++c) {
        for (int ty = threadIdx.y; ty < TILE_H; ty += NTY) {
            const int gy = reflect_idx(by0 + ty - 3, HH);
            const float* grow = inb + (c * HH + gy) * WW;
            float* srow = &sm[(c * TILE_H + ty) * PHYS_W];
            for (int tx = threadIdx.x; tx < TILE_W; tx += NTX) {
                const int gx = reflect_idx(bx0 + tx - 3, WW);
                srow[phys(tx)] = grow[gx];
            }
        }
    }
    __syncthreads();

    const int lx = threadIdx.x;
    const int rb = threadIdx.y * PYT;       // first pixel row (tile coords) of this thread
    const int cb = PXT * lx;                // first window col

    // per-lane skewed dword offsets (incl. thread row base), made OPAQUE so the
    // compiler cannot prove adjacency and re-vectorize into conflicting ds_read_b64
    int vcol[8];
#pragma unroll
    for (int k = 0; k < 8; ++k) {
        vcol[k] = rb * PHYS_W + phys(cb + k);
        asm("" : "+v"(vcol[k]));
    }

    // center values for the 8 pixels
    float cc0[PYT][PXT], cc1[PYT][PXT], cc2[PYT][PXT];
#pragma unroll
    for (int py = 0; py < PYT; ++py) {
#pragma unroll
        for (int p = 0; p < PXT; ++p) {
            cc0[py][p] = sm[(0 * TILE_H + py + 3) * PHYS_W + vcol[3 + p]];
            cc1[py][p] = sm[(1 * TILE_H + py + 3) * PHYS_W + vcol[3 + p]];
            cc2[py][p] = sm[(2 * TILE_H + py + 3) * PHYS_W + vcol[3 + p]];
        }
    }

    float n0[PYT][PXT] = {}, n1[PYT][PXT] = {}, n2[PYT][PXT] = {}, den[PYT][PXT] = {};

    // slide over the 10 tile rows this thread's 4 pixel-windows touch
#pragma unroll
    for (int r = 0; r < PYT + 6; ++r) {
        float A0[8], A1[8], A2[8];
#pragma unroll
        for (int k = 0; k < 8; ++k) {
            A0[k] = sm[(0 * TILE_H + r) * PHYS_W + vcol[k]];
            A1[k] = sm[(1 * TILE_H + r) * PHYS_W + vcol[k]];
            A2[k] = sm[(2 * TILE_H + r) * PHYS_W + vcol[k]];
        }
#pragma unroll
        for (int py = 0; py < PYT; ++py) {
            const int i = r - py;           // kernel row for pixel-row py
            if (i < 0 || i > 6) continue;   // compile-time pruned
#pragma unroll
            for (int j = 0; j < 7; ++j) {
#pragma unroll
                for (int p = 0; p < PXT; ++p) {
                    const float v0 = A0[j + p];
                    const float v1 = A1[j + p];
                    const float v2 = A2[j + p];
                    const float d  = fabsf(v0 - cc0[py][p]) + fabsf(v1 - cc1[py][p]) + fabsf(v2 - cc2[py][p]);
                    const float lnw = (float)((i - 3) * (i - 3) + (j - 3) * (j - 3)) * K2f;
                    const float w  = fast_exp2(fmaf(d * K1f, d, lnw));
                    n0[py][p]  = fmaf(w, v0, n0[py][p]);
                    n1[py][p]  = fmaf(w, v1, n1[py][p]);
                    n2[py][p]  = fmaf(w, v2, n2[py][p]);
                    den[py][p] += w;
                }
            }
        }
    }

    float* outb = out + (size_t)b * CH * HH * WW;
    const int x0 = bx0 + cb;
#pragma unroll
    for (int py = 0; py < PYT; ++py) {
        const int y = by0 + rb + py;
        const float i0 = 1.0f / den[py][0];   // den >= 1 (center tap w == 1)
        const float i1 = 1.0f / den[py][1];
        float2 o;
        o.x = n0[py][0] * i0; o.y = n0[py][1] * i1;
        *reinterpret_cast<float2*>(&outb[(0 * HH + y) * WW + x0]) = o;
        o.x = n1[py][0] * i0; o.y = n1[py][1] * i1;
        *reinterpret_cast<float2*>(&outb[(1 * HH + y) * WW + x0]) = o;
        o.x = n2[py][0] * i0; o.y = n2[py][1] * i1;
        *reinterpret_cast<float2*>(&outb[(2 * HH + y) * WW + x0]) = o;
    }
}

extern "C" void kernel_launch(void* const* d_in, const int* in_sizes, int n_in,
                              void* d_out, int out_size, void* d_ws, size_t ws_size,
                              hipStream_t stream) {
    const float* in = (const float*)d_in[0];
    float* out = (float*)d_out;
    const int B = in_sizes[0] / (CH * HH * WW);
    dim3 grid(WW / SPANX, HH / SPANY, B);
    dim3 block(NTX, NTY, 1);
    bilateral_kernel<<<grid, block, 0, stream>>>(in, out);
}

// Round 6
// 81.998 us; speedup vs baseline: 2.4468x; 2.4468x over previous
//
#include <hip/hip_runtime.h>

#define HH 512
#define WW 512
#define CH 3
#define NTX 64           // one column per lane -> all LDS reads lane-stride-1 (R0's proven pattern)
#define NTY 4
#define PY  4            // vertical pixels per thread
#define SPANY (NTY * PY)         // 16 rows per block
#define TILE_W 70                // 64 + 6 halo
#define TILE_H (SPANY + 6)       // 22
#define NELEM (CH * TILE_H * TILE_W)   // 4620 floats = 18480 B

// exp(-50*d^2) * exp(-r2/4.5) == exp2(K1*d^2 + K2*r2)
#define K1f (-72.13475204444817f)   // -50 * log2(e)
#define K2f (-0.3205988979753252f)  // -(1/4.5) * log2(e)

__device__ __forceinline__ int reflect_idx(int v, int n) {
    v = (v < 0) ? -v : v;
    return (v >= n) ? (2 * (n - 1) - v) : v;
}

__device__ __forceinline__ float fast_exp2(float x) {
#if __has_builtin(__builtin_amdgcn_exp2f)
    return __builtin_amdgcn_exp2f(x);
#else
    return exp2f(x);
#endif
}

__global__ __launch_bounds__(NTX * NTY)
void bilateral_kernel(const float* __restrict__ in, float* __restrict__ out) {
    __shared__ float sm[NELEM];

    const int bx0 = blockIdx.x * NTX;
    const int by0 = blockIdx.y * SPANY;
    const int b   = blockIdx.z;
    const int tid = threadIdx.y * NTX + threadIdx.x;
    const float* inb = in + (size_t)b * CH * HH * WW;

    // ---- cooperative halo staging (lane-stride-1 b32 writes: conflict-free) ----
    for (int idx = tid; idx < NELEM; idx += NTX * NTY) {
        int c  = idx / (TILE_H * TILE_W);
        int r  = idx - c * (TILE_H * TILE_W);
        int ty = r / TILE_W;
        int tx = r - ty * TILE_W;
        const int gy = reflect_idx(by0 + ty - 3, HH);
        const int gx = reflect_idx(bx0 + tx - 3, WW);
        sm[idx] = inb[(c * HH + gy) * WW + gx];
    }
    __syncthreads();

    const int lx = threadIdx.x;
    const int rb = threadIdx.y * PY;     // first pixel row (tile coords) of this thread

    // single LDS base; every read below is base + compile-time immediate
    const float* smb = sm + rb * TILE_W + lx;
#define SMEM(c, r, j) smb[((c) * TILE_H + (r)) * TILE_W + (j)]

    // center values: pixel py center = tile row rb+py+3, col lx+3
    float c0[PY], c1[PY], c2[PY];
#pragma unroll
    for (int py = 0; py < PY; ++py) {
        c0[py] = SMEM(0, py + 3, 3);
        c1[py] = SMEM(1, py + 3, 3);
        c2[py] = SMEM(2, py + 3, 3);
    }

    float n0[PY] = {}, n1[PY] = {}, n2[PY] = {}, den[PY] = {};

#pragma unroll
    for (int r = 0; r < PY + 6; ++r) {
        // 21 lane-stride-1 scalar reads, shared by all pixel rows touching tile row r
        float A0[7], A1[7], A2[7];
#pragma unroll
        for (int j = 0; j < 7; ++j) {
            A0[j] = SMEM(0, r, j);
            A1[j] = SMEM(1, r, j);
            A2[j] = SMEM(2, r, j);
        }
#pragma unroll
        for (int py = 0; py < PY; ++py) {
            const int i = r - py;            // kernel row for pixel-row py
            if (i < 0 || i > 6) continue;    // compile-time pruned
#pragma unroll
            for (int j = 0; j < 7; ++j) {
                const float v0 = A0[j];
                const float v1 = A1[j];
                const float v2 = A2[j];
                const float d  = fabsf(v0 - c0[py]) + fabsf(v1 - c1[py]) + fabsf(v2 - c2[py]);
                const float LK = (float)((i - 3) * (i - 3) + (j - 3) * (j - 3)) * K2f;
                const float w  = fast_exp2(fmaf(d * K1f, d, LK));
                n0[py]  = fmaf(w, v0, n0[py]);
                n1[py]  = fmaf(w, v1, n1[py]);
                n2[py]  = fmaf(w, v2, n2[py]);
                den[py] += w;
            }
        }
    }
#undef SMEM

    float* outb = out + (size_t)b * CH * HH * WW;
    const int x = bx0 + lx;
#pragma unroll
    for (int py = 0; py < PY; ++py) {
        const int y = by0 + rb + py;
        const float inv = 1.0f / den[py];    // den >= 1 (center tap w == 1)
        outb[(0 * HH + y) * WW + x] = n0[py] * inv;
        outb[(1 * HH + y) * WW + x] = n1[py] * inv;
        outb[(2 * HH + y) * WW + x] = n2[py] * inv;
    }
}

extern "C" void kernel_launch(void* const* d_in, const int* in_sizes, int n_in,
                              void* d_out, int out_size, void* d_ws, size_t ws_size,
                              hipStream_t stream) {
    const float* in = (const float*)d_in[0];
    float* out = (float*)d_out;
    const int B = in_sizes[0] / (CH * HH * WW);
    dim3 grid(WW / NTX, HH / SPANY, B);
    dim3 block(NTX, NTY, 1);
    bilateral_kernel<<<grid, block, 0, stream>>>(in, out);
}

// Round 7
// 56.083 us; speedup vs baseline: 3.5774x; 1.4621x over previous
//
#include <hip/hip_runtime.h>

#define HH 512
#define WW 512
#define CH 3
#define NTX 64           // one column per lane -> lane-stride-1 LDS (proven conflict-free)
#define NTY 4
#define PY  4            // vertical pixels per thread
#define SPANY (NTY * PY)         // 16 rows per block
#define TILE_W 70                // 64 + 6 halo
#define TILE_H (SPANY + 6)       // 22
#define CSTR (TILE_H * TILE_W)   // channel stride in floats (1540)

// exp(-50*d^2 - ((i-3)^2+(j-3)^2)/4.5) == exp2(K1*d^2 + K2*(i-3)^2) * WJ[j]
#define K1f (-72.13475204444817f)   // -50 * log2(e)
#define K2f (-0.3205988979753252f)  // -(1/4.5) * log2(e)

__device__ __constant__ const float WJ[7] = {
    0.13533528323661270f,  // exp(-9/4.5)
    0.41111229050718745f,  // exp(-4/4.5)
    0.80073740291680804f,  // exp(-1/4.5)
    1.0f,
    0.80073740291680804f,
    0.41111229050718745f,
    0.13533528323661270f
};

__device__ __forceinline__ int reflect_idx(int v, int n) {
    v = (v < 0) ? -v : v;
    return (v >= n) ? (2 * (n - 1) - v) : v;
}

__device__ __forceinline__ float fast_exp2(float x) {
#if __has_builtin(__builtin_amdgcn_exp2f)
    return __builtin_amdgcn_exp2f(x);
#else
    return exp2f(x);
#endif
}

__global__ __launch_bounds__(NTX * NTY)
void bilateral_kernel(const float* __restrict__ in, float* __restrict__ out) {
    __shared__ float sm[CH * CSTR];   // 18480 B

    const int bx0 = blockIdx.x * NTX;
    const int by0 = blockIdx.y * SPANY;
    const int b   = blockIdx.z;
    const int lx  = threadIdx.x;
    const float* inb = in + (size_t)b * CH * HH * WW;

    // ---- cooperative halo staging (lane-stride-1 b32 writes: conflict-free) ----
    for (int c = 0; c < CH; ++c) {
        for (int ty = threadIdx.y; ty < TILE_H; ty += NTY) {
            const int gy = reflect_idx(by0 + ty - 3, HH);
            const float* grow = inb + (c * HH + gy) * WW;
            float* srow = &sm[c * CSTR + ty * TILE_W];
            const int gx0 = reflect_idx(bx0 + lx - 3, WW);
            srow[lx] = grow[gx0];
            if (lx < TILE_W - NTX) {
                const int gx1 = reflect_idx(bx0 + lx + NTX - 3, WW);
                srow[lx + NTX] = grow[gx1];
            }
        }
    }
    __syncthreads();

    const int rb = threadIdx.y * PY;            // first pixel row (tile coords)
    const float* smb = sm + rb * TILE_W + lx;   // single per-lane base

    // center values (compile-time offsets)
    float c0[PY], c1[PY], c2[PY];
#pragma unroll
    for (int py = 0; py < PY; ++py) {
        c0[py] = smb[0 * CSTR + (py + 3) * TILE_W + 3];
        c1[py] = smb[1 * CSTR + (py + 3) * TILE_W + 3];
        c2[py] = smb[2 * CSTR + (py + 3) * TILE_W + 3];
    }

    float n0[PY] = {}, n1[PY] = {}, n2[PY] = {}, den[PY] = {};

    const float* rowp = smb;
    // NOT unrolled: keeps only one row's 21 values live -> bounded VGPR
#pragma unroll 1
    for (int r = 0; r < PY + 6; ++r) {
        float A0[7], A1[7], A2[7];
#pragma unroll
        for (int j = 0; j < 7; ++j) {
            A0[j] = rowp[0 * CSTR + j];
            A1[j] = rowp[1 * CSTR + j];
            A2[j] = rowp[2 * CSTR + j];
        }
#pragma unroll
        for (int py = 0; py < PY; ++py) {
            const int i = r - py;                 // kernel row for pixel-row py (wave-uniform)
            if (0 <= i && i <= 6) {
                const int im3 = i - 3;
                const float ikK2 = (float)(im3 * im3) * K2f;
#pragma unroll
                for (int j = 0; j < 7; ++j) {
                    const float v0 = A0[j], v1 = A1[j], v2 = A2[j];
                    const float d  = fabsf(v0 - c0[py]) + fabsf(v1 - c1[py]) + fabsf(v2 - c2[py]);
                    const float wp = fast_exp2(fmaf(d * K1f, d, ikK2));
                    const float w  = wp * WJ[j];
                    n0[py]  = fmaf(w, v0, n0[py]);
                    n1[py]  = fmaf(w, v1, n1[py]);
                    n2[py]  = fmaf(w, v2, n2[py]);
                    den[py] += w;
                }
            }
        }
        rowp += TILE_W;
    }

    float* outb = out + (size_t)b * CH * HH * WW;
    const int x = bx0 + lx;
#pragma unroll
    for (int py = 0; py < PY; ++py) {
        const int y = by0 + rb + py;
        const float inv = 1.0f / den[py];   // den >= 1 (center tap w == 1)
        outb[(0 * HH + y) * WW + x] = n0[py] * inv;
        outb[(1 * HH + y) * WW + x] = n1[py] * inv;
        outb[(2 * HH + y) * WW + x] = n2[py] * inv;
    }
}

extern "C" void kernel_launch(void* const* d_in, const int* in_sizes, int n_in,
                              void* d_out, int out_size, void* d_ws, size_t ws_size,
                              hipStream_t stream) {
    const float* in = (const float*)d_in[0];
    float* out = (float*)d_out;
    const int B = in_sizes[0] / (CH * HH * WW);
    dim3 grid(WW / NTX, HH / SPANY, B);
    dim3 block(NTX, NTY, 1);
    bilateral_kernel<<<grid, block, 0, stream>>>(in, out);
}